// Round 4
// baseline (201.641 us; speedup 1.0000x reference)
//
#include <hip/hip_runtime.h>
#include <hip/hip_bf16.h>

typedef __bf16 bf16x8_t __attribute__((ext_vector_type(8)));
typedef float f32x4_t __attribute__((ext_vector_type(4)));
using bf16 = __hip_bfloat16;

#define ASG __attribute__((address_space(1)))
#define ASL __attribute__((address_space(3)))

__device__ __forceinline__ void gld_lds16(const void* g, void* l) {
  // lane i of the wave lands at (wave-uniform lds base) + i*16 bytes; src is per-lane.
  __builtin_amdgcn_global_load_lds((ASG void*)const_cast<void*>(g),
                                   (ASL void*)l, 16, 0, 0);
}

__device__ __forceinline__ unsigned short f2bf_bits(float v) {
  __hip_bfloat16 h = __float2bfloat16(v);
  return *reinterpret_cast<unsigned short*>(&h);
}

// 13 cubic B-spline basis values (grid 10, k=3, [-2,2]) + mish -> 28B LDS region.
// dst must be 4B-aligned.
__device__ __forceinline__ void kan_feats28(bf16* dst, float x) {
  unsigned int* d32 = (unsigned int*)dst;
#pragma unroll
  for (int d = 0; d < 7; ++d) d32[d] = 0u;
  float t = (x + 3.2f) * 2.5f;
  if (t >= 0.0f && t < 16.0f) {
    float tf = floorf(t);
    int c = (int)tf;
    float u = t - tf;
    float um = 1.0f - u;
    float u2 = u * u, u3 = u2 * u;
    const float s6 = 1.0f / 6.0f;
    float w0 = um * um * um * s6;
    float w1 = (3.0f * u3 - 6.0f * u2 + 4.0f) * s6;
    float w2 = (-3.0f * u3 + 3.0f * u2 + 3.0f * u + 1.0f) * s6;
    float w3 = u3 * s6;
    int j0 = c - 3;
    if (j0 >= 0)               dst[j0]     = __float2bfloat16(w0);
    if (j0 >= -1 && j0 <= 11)  dst[j0 + 1] = __float2bfloat16(w1);
    if (j0 >= -2 && j0 <= 10)  dst[j0 + 2] = __float2bfloat16(w2);
    if (j0 <= 9)               dst[j0 + 3] = __float2bfloat16(w3);
  }
  float sp = (x > 20.0f) ? x : log1pf(expf(x));
  dst[13] = __float2bfloat16(x * tanhf(sp));
}

// One dispatch builds all three weight matrices, coalesced coef reads.
// W[o][i*14+r] = r<13 ? coef[i][o][r]*sp[i][o] : sb[i][o]; pads zeroed.
__global__ __launch_bounds__(256) void prep_all(
    const float* __restrict__ c1, const float* __restrict__ sb1, const float* __restrict__ sp1,
    const float* __restrict__ c2, const float* __restrict__ sb2, const float* __restrict__ sp2,
    const float* __restrict__ c3, const float* __restrict__ sb3, const float* __restrict__ sp3,
    bf16* __restrict__ W1t, bf16* __restrict__ W2t, bf16* __restrict__ W3t) {
  const int b = blockIdx.x, o = threadIdx.x;
  float vals[14];
  if (b < 49) {
    const int i = b;
    const size_t io = (size_t)i * 256 + o;
    const float spv = sp1[io];
#pragma unroll
    for (int r = 0; r < 13; ++r) vals[r] = c1[io * 13 + r] * spv;
    vals[13] = sb1[io];
    unsigned int* dst = (unsigned int*)(W1t + (size_t)o * 704 + i * 14);
#pragma unroll
    for (int d = 0; d < 7; ++d)
      dst[d] = (unsigned int)f2bf_bits(vals[2 * d]) |
               ((unsigned int)f2bf_bits(vals[2 * d + 1]) << 16);
  } else if (b == 49) {
    unsigned int* dst = (unsigned int*)(W1t + (size_t)o * 704 + 686);
#pragma unroll
    for (int d = 0; d < 9; ++d) dst[d] = 0u;  // K-pad 686..703
  } else if (b < 306) {
    const int i = b - 50;
    const size_t io = (size_t)i * 256 + o;
    const float spv = sp2[io];
#pragma unroll
    for (int r = 0; r < 13; ++r) vals[r] = c2[io * 13 + r] * spv;
    vals[13] = sb2[io];
    unsigned int* dst = (unsigned int*)(W2t + (size_t)o * 3584 + i * 14);
#pragma unroll
    for (int d = 0; d < 7; ++d)
      dst[d] = (unsigned int)f2bf_bits(vals[2 * d]) |
               ((unsigned int)f2bf_bits(vals[2 * d + 1]) << 16);
  } else {
    const int i = b - 306;
    if (o < 10) {
      const size_t io = (size_t)i * 10 + o;
      const float spv = sp3[io];
#pragma unroll
      for (int r = 0; r < 13; ++r) vals[r] = c3[io * 13 + r] * spv;
      vals[13] = sb3[io];
      unsigned int* dst = (unsigned int*)(W3t + (size_t)o * 3584 + i * 14);
#pragma unroll
      for (int d = 0; d < 7; ++d)
        dst[d] = (unsigned int)f2bf_bits(vals[2 * d]) |
                 ((unsigned int)f2bf_bits(vals[2 * d + 1]) << 16);
    } else if (o < 16) {
      unsigned int* dst = (unsigned int*)(W3t + (size_t)o * 3584 + i * 14);
#pragma unroll
      for (int d = 0; d < 7; ++d) dst[d] = 0u;  // N-pad rows 10..15
    }
  }
}

// One block per image: 4x4 avg-pool 28x28 -> 49, basis+mish -> A1 row (704 bf16).
__global__ __launch_bounds__(256) void pool_basis1(const float* __restrict__ x,
                                                   bf16* __restrict__ A1) {
  __shared__ __align__(16) float xs[784];
  __shared__ __align__(16) bf16 arow[704];
  const int b = blockIdx.x, t = threadIdx.x;
  if (t < 196) *(float4*)(&xs[t * 4]) = *(const float4*)(x + (size_t)b * 784 + t * 4);
  __syncthreads();
  if (t < 49) {
    const int oh = t / 7, ow = t % 7;
    float s = 0.f;
#pragma unroll
    for (int r = 0; r < 4; ++r)
#pragma unroll
      for (int c = 0; c < 4; ++c) s += xs[(oh * 4 + r) * 28 + ow * 4 + c];
    kan_feats28(&arow[t * 14], s * (1.0f / 16.0f));
  } else if (t < 67) {
    arow[686 + (t - 49)] = __float2bfloat16(0.0f);  // K pad 686..703
  }
  __syncthreads();
  if (t < 88) ((uint4*)((char*)A1 + (size_t)b * 1408))[t] = ((const uint4*)arow)[t];
}

// Layer-1 GEMM (K=704, BK=64, XOR-swizzled LDS — proven R3 structure), bias added.
__global__ __launch_bounds__(256) void gemm1s(
    const bf16* __restrict__ A, const bf16* __restrict__ Wt,
    const float* __restrict__ bias, float* __restrict__ H) {
  constexpr int K = 704;
  __shared__ __align__(16) bf16 As[64 * 64];
  __shared__ __align__(16) bf16 Bs[64 * 64];
  const int t = threadIdx.x;
  const int wv = t >> 6, lane = t & 63, quad = lane >> 4, lr = lane & 15;
  const int n0 = blockIdx.x * 64;
  const int m0 = blockIdx.y * 64;
  const int srow0 = lane >> 3;
  const int cg = (lane & 7) ^ srow0;
  const bf16* gA0 = A + (size_t)(m0 + 8 * wv + srow0) * K + cg * 8;
  const bf16* gA1 = A + (size_t)(m0 + 32 + 8 * wv + srow0) * K + cg * 8;
  const bf16* gB0 = Wt + (size_t)(n0 + 8 * wv + srow0) * K + cg * 8;
  const bf16* gB1 = Wt + (size_t)(n0 + 32 + 8 * wv + srow0) * K + cg * 8;
  char* const lA = (char*)As + wv * 1024;
  char* const lB = (char*)Bs + wv * 1024;
  const int wm = (wv & 1) * 32, wn = (wv >> 1) * 32;
  const int swz = lr & 7;
  f32x4_t acc00 = {0.f, 0.f, 0.f, 0.f}, acc01 = acc00, acc10 = acc00, acc11 = acc00;
  for (int k0 = 0; k0 < K; k0 += 64) {
    gld_lds16(gA0 + k0, lA);
    gld_lds16(gA1 + k0, lA + 4096);
    gld_lds16(gB0 + k0, lB);
    gld_lds16(gB1 + k0, lB + 4096);
    __syncthreads();
#pragma unroll
    for (int s = 0; s < 2; ++s) {
      const int co = ((s * 4 + quad) ^ swz) * 16;
      bf16x8_t a0 = *(const bf16x8_t*)((char*)As + (wm + lr) * 128 + co);
      bf16x8_t a1 = *(const bf16x8_t*)((char*)As + (wm + 16 + lr) * 128 + co);
      bf16x8_t b0 = *(const bf16x8_t*)((char*)Bs + (wn + lr) * 128 + co);
      bf16x8_t b1 = *(const bf16x8_t*)((char*)Bs + (wn + 16 + lr) * 128 + co);
      acc00 = __builtin_amdgcn_mfma_f32_16x16x32_bf16(a0, b0, acc00, 0, 0, 0);
      acc01 = __builtin_amdgcn_mfma_f32_16x16x32_bf16(a0, b1, acc01, 0, 0, 0);
      acc10 = __builtin_amdgcn_mfma_f32_16x16x32_bf16(a1, b0, acc10, 0, 0, 0);
      acc11 = __builtin_amdgcn_mfma_f32_16x16x32_bf16(a1, b1, acc11, 0, 0, 0);
    }
    __syncthreads();
  }
  const int cb = n0 + wn + lr;
  const float bn0 = bias[cb], bn1 = bias[cb + 16];
#pragma unroll
  for (int r = 0; r < 4; ++r) {
    const size_t row = (size_t)(m0 + wm + quad * 4 + r);
    H[row * 256 + cb] = acc00[r] + bn0;
    H[row * 256 + cb + 16] = acc01[r] + bn1;
    H[(row + 16) * 256 + cb] = acc10[r] + bn0;
    H[(row + 16) * 256 + cb + 16] = acc11[r] + bn1;
  }
}

// Fused KAN layer (256->256): reads H fp32, computes feats into padded LDS A
// (row stride 464B: bank-balanced), stages W via gld_lds into XOR-swizzled B
// (row stride 512B, slot = chunk^(row&7)), MFMA in 16 chunks of K=224.
__global__ __launch_bounds__(256) void kan_gemm2(
    const float* __restrict__ Hin, const bf16* __restrict__ Wt,
    const float* __restrict__ bias, float* __restrict__ Hout) {
  constexpr int K = 3584;
  __shared__ __align__(16) bf16 As[64 * 232];  // 29696 B
  __shared__ __align__(16) bf16 Bs[64 * 256];  // 32768 B
  const int t = threadIdx.x;
  const int wv = t >> 6, lane = t & 63, quad = lane >> 4, lr = lane & 15;
  const int n0 = blockIdx.x * 64, m0 = blockIdx.y * 64;
  const int wm = (wv & 1) * 32, wn = (wv >> 1) * 32;
  const int ej = t & 15, er0 = t >> 4;
  const int brow_sub = lane >> 5, bslot = lane & 31;
  f32x4_t acc00 = {0.f, 0.f, 0.f, 0.f}, acc01 = acc00, acc10 = acc00, acc11 = acc00;
  for (int kc = 0; kc < 16; ++kc) {
    // stage B chunk: 64 rows x 28 chunks (+4 junk) at stride 512B, swizzled
#pragma unroll
    for (int n = 0; n < 8; ++n) {
      const int row = wv * 16 + n * 2 + brow_sub;
      int c = bslot ^ (row & 7);
      if (c >= 28) c = 0;  // junk slot, never read
      const bf16* src = Wt + (size_t)(n0 + row) * K + kc * 224 + c * 8;
      gld_lds16(src, (char*)Bs + (wv * 16 + n * 2) * 512);
    }
    // compute A feats for this chunk: 64 rows x 16 inputs, 4 evals/thread
    const float* hp = Hin + (size_t)(m0 + er0) * 256 + kc * 16 + ej;
    bf16* arow = As + er0 * 232 + ej * 14;
#pragma unroll
    for (int e = 0; e < 4; ++e) kan_feats28(arow + e * 16 * 232, hp[e * 16 * 256]);
    __syncthreads();
#pragma unroll
    for (int ks = 0; ks < 7; ++ks) {
      const int coA = ks * 64 + quad * 16;
      const int sb = ((ks * 4 + quad) ^ (lr & 7)) * 16;
      bf16x8_t a0 = *(const bf16x8_t*)((const char*)As + (wm + lr) * 464 + coA);
      bf16x8_t a1 = *(const bf16x8_t*)((const char*)As + (wm + 16 + lr) * 464 + coA);
      bf16x8_t b0 = *(const bf16x8_t*)((const char*)Bs + (wn + lr) * 512 + sb);
      bf16x8_t b1 = *(const bf16x8_t*)((const char*)Bs + (wn + 16 + lr) * 512 + sb);
      acc00 = __builtin_amdgcn_mfma_f32_16x16x32_bf16(a0, b0, acc00, 0, 0, 0);
      acc01 = __builtin_amdgcn_mfma_f32_16x16x32_bf16(a0, b1, acc01, 0, 0, 0);
      acc10 = __builtin_amdgcn_mfma_f32_16x16x32_bf16(a1, b0, acc10, 0, 0, 0);
      acc11 = __builtin_amdgcn_mfma_f32_16x16x32_bf16(a1, b1, acc11, 0, 0, 0);
    }
    __syncthreads();
  }
  const int cb = n0 + wn + lr;
  const float bn0 = bias[cb], bn1 = bias[cb + 16];
#pragma unroll
  for (int r = 0; r < 4; ++r) {
    const size_t row = (size_t)(m0 + wm + quad * 4 + r);
    Hout[row * 256 + cb] = acc00[r] + bn0;
    Hout[row * 256 + cb + 16] = acc01[r] + bn1;
    Hout[(row + 16) * 256 + cb] = acc10[r] + bn0;
    Hout[(row + 16) * 256 + cb + 16] = acc11[r] + bn1;
  }
}

// Fused layer 3: M=64 tile, N=16 (10 real), split-K over blockIdx.y (4 x 4 chunks).
// partials [z][n][m] for coalesced reduction.
__global__ __launch_bounds__(256) void kan_gemm3(
    const float* __restrict__ Hin, const bf16* __restrict__ Wt,
    float* __restrict__ part) {
  constexpr int K = 3584;
  __shared__ __align__(16) bf16 As[64 * 232];
  __shared__ __align__(16) bf16 Bs[16 * 256];
  const int t = threadIdx.x;
  const int wv = t >> 6, lane = t & 63, quad = lane >> 4, lr = lane & 15;
  const int m0 = blockIdx.x * 64;
  const int z = blockIdx.y;
  const int ej = t & 15, er0 = t >> 4;
  const int brow_sub = lane >> 5, bslot = lane & 31;
  f32x4_t acc = {0.f, 0.f, 0.f, 0.f};
  for (int kcl = 0; kcl < 4; ++kcl) {
    const int kc = z * 4 + kcl;
#pragma unroll
    for (int n = 0; n < 2; ++n) {
      const int row = wv * 4 + n * 2 + brow_sub;
      int c = bslot ^ (row & 7);
      if (c >= 28) c = 0;
      const bf16* src = Wt + (size_t)row * K + kc * 224 + c * 8;
      gld_lds16(src, (char*)Bs + (wv * 4 + n * 2) * 512);
    }
    const float* hp = Hin + (size_t)(m0 + er0) * 256 + kc * 16 + ej;
    bf16* arow = As + er0 * 232 + ej * 14;
#pragma unroll
    for (int e = 0; e < 4; ++e) kan_feats28(arow + e * 16 * 232, hp[e * 16 * 256]);
    __syncthreads();
#pragma unroll
    for (int ks = 0; ks < 7; ++ks) {
      const int coA = ks * 64 + quad * 16;
      const int sb = ((ks * 4 + quad) ^ (lr & 7)) * 16;
      bf16x8_t a = *(const bf16x8_t*)((const char*)As + (wv * 16 + lr) * 464 + coA);
      bf16x8_t b = *(const bf16x8_t*)((const char*)Bs + lr * 512 + sb);
      acc = __builtin_amdgcn_mfma_f32_16x16x32_bf16(a, b, acc, 0, 0, 0);
    }
    __syncthreads();
  }
#pragma unroll
  for (int r = 0; r < 4; ++r)
    part[(size_t)z * 131072 + (size_t)lr * 8192 + (m0 + wv * 16 + quad * 4 + r)] = acc[r];
}

// Reduce 4 split-K partials + bias, log_softmax over 10 classes.
__global__ __launch_bounds__(256) void lsm(const float* __restrict__ part,
                                           const float* __restrict__ b3,
                                           float* __restrict__ out) {
  const int row = blockIdx.x * 256 + threadIdx.x;
  float v[10];
#pragma unroll
  for (int o = 0; o < 10; ++o) {
    float s = b3[o];
#pragma unroll
    for (int kc = 0; kc < 4; ++kc) s += part[(size_t)kc * 131072 + (size_t)o * 8192 + row];
    v[o] = s;
  }
  float m = v[0];
#pragma unroll
  for (int o = 1; o < 10; ++o) m = fmaxf(m, v[o]);
  float se = 0.f;
#pragma unroll
  for (int o = 0; o < 10; ++o) se += expf(v[o] - m);
  const float l = m + logf(se);
#pragma unroll
  for (int o = 0; o < 10; ++o) out[(size_t)row * 10 + o] = v[o] - l;
}

extern "C" void kernel_launch(void* const* d_in, const int* in_sizes, int n_in,
                              void* d_out, int out_size, void* d_ws, size_t ws_size,
                              hipStream_t stream) {
  const float* x = (const float*)d_in[0];
  const float* coef1 = (const float*)d_in[1];
  const float* sb1 = (const float*)d_in[2];
  const float* sp1 = (const float*)d_in[3];
  const float* b1 = (const float*)d_in[4];
  const float* coef2 = (const float*)d_in[5];
  const float* sb2 = (const float*)d_in[6];
  const float* sp2 = (const float*)d_in[7];
  const float* b2 = (const float*)d_in[8];
  const float* coef3 = (const float*)d_in[9];
  const float* sb3 = (const float*)d_in[10];
  const float* sp3 = (const float*)d_in[11];
  const float* b3 = (const float*)d_in[12];
  float* out = (float*)d_out;

  char* ws = (char*)d_ws;
  size_t off = 0;
  bf16* A1 = (bf16*)(ws + off);    off += 11534336;  // 8192*704*2
  bf16* W1t = (bf16*)(ws + off);   off += 360448;    // 256*704*2
  bf16* W2t = (bf16*)(ws + off);   off += 1835008;   // 256*3584*2
  bf16* W3t = (bf16*)(ws + off);   off += 114688;    // 16*3584*2
  float* H1 = (float*)(ws + off);  off += 8388608;   // 8192*256*4
  float* H2 = (float*)(ws + off);  off += 8388608;
  float* part = (float*)(ws + off); off += 2097152;  // 4*16*8192*4

  prep_all<<<562, 256, 0, stream>>>(coef1, sb1, sp1, coef2, sb2, sp2,
                                    coef3, sb3, sp3, W1t, W2t, W3t);
  pool_basis1<<<8192, 256, 0, stream>>>(x, A1);
  gemm1s<<<dim3(4, 128), 256, 0, stream>>>(A1, W1t, b1, H1);
  kan_gemm2<<<dim3(4, 128), 256, 0, stream>>>(H1, W2t, b2, H2);
  kan_gemm3<<<dim3(128, 4), 256, 0, stream>>>(H2, W3t, part);
  lsm<<<32, 256, 0, stream>>>(part, b3, out);
}

// Round 5
// 187.226 us; speedup vs baseline: 1.0770x; 1.0770x over previous
//
#include <hip/hip_runtime.h>
#include <hip/hip_bf16.h>

typedef __bf16 bf16x8_t __attribute__((ext_vector_type(8)));
typedef float f32x4_t __attribute__((ext_vector_type(4)));
using bf16 = __hip_bfloat16;

#define ASG __attribute__((address_space(1)))
#define ASL __attribute__((address_space(3)))

__device__ __forceinline__ void gld_lds16(const void* g, void* l) {
  // lane i of the wave lands at (wave-uniform lds base) + i*16 bytes; src is per-lane.
  __builtin_amdgcn_global_load_lds((ASG void*)const_cast<void*>(g),
                                   (ASL void*)l, 16, 0, 0);
}

__device__ __forceinline__ unsigned short f2bf_bits(float v) {
  __hip_bfloat16 h = __float2bfloat16(v);
  return *reinterpret_cast<unsigned short*>(&h);
}

// mish(x) = x*tanh(softplus(x)) = x*n/(n+2) with n = e^x*(e^x+2).
// (tanh(log1p(e^x)) algebraically; guard large x where e^{2x} overflows.)
__device__ __forceinline__ float mish_f(float x) {
  float z = __expf(x);
  float n = z * (z + 2.0f);
  float m = x * n / (n + 2.0f);
  return (x > 10.0f) ? x : m;
}

// 13 cubic B-spline basis values (grid 10, k=3, [-2,2]) + mish -> 28B LDS region.
// dst must be 4B-aligned.
__device__ __forceinline__ void kan_feats28(bf16* dst, float x) {
  unsigned int* d32 = (unsigned int*)dst;
#pragma unroll
  for (int d = 0; d < 7; ++d) d32[d] = 0u;
  float t = (x + 3.2f) * 2.5f;
  if (t >= 0.0f && t < 16.0f) {
    float tf = floorf(t);
    int c = (int)tf;
    float u = t - tf;
    float um = 1.0f - u;
    float u2 = u * u, u3 = u2 * u;
    const float s6 = 1.0f / 6.0f;
    float w0 = um * um * um * s6;
    float w1 = (3.0f * u3 - 6.0f * u2 + 4.0f) * s6;
    float w2 = (-3.0f * u3 + 3.0f * u2 + 3.0f * u + 1.0f) * s6;
    float w3 = u3 * s6;
    int j0 = c - 3;
    if (j0 >= 0)               dst[j0]     = __float2bfloat16(w0);
    if (j0 >= -1 && j0 <= 11)  dst[j0 + 1] = __float2bfloat16(w1);
    if (j0 >= -2 && j0 <= 10)  dst[j0 + 2] = __float2bfloat16(w2);
    if (j0 <= 9)               dst[j0 + 3] = __float2bfloat16(w3);
  }
  dst[13] = __float2bfloat16(mish_f(x));
}

// Builds W1t (row-major K=704), W2f (MFMA-fragment-major), W3t (row-major).
// W2f fragment (kc,ks,ntg) = 16 rows x 32 k, 1KB contiguous; element (lr,quad,el)
// at frag*512 + lr*32 + quad*8 + el. k' = i*14+r is even for r even -> pair dwords.
__global__ __launch_bounds__(256) void prep_all(
    const float* __restrict__ c1, const float* __restrict__ sb1, const float* __restrict__ sp1,
    const float* __restrict__ c2, const float* __restrict__ sb2, const float* __restrict__ sp2,
    const float* __restrict__ c3, const float* __restrict__ sb3, const float* __restrict__ sp3,
    bf16* __restrict__ W1t, bf16* __restrict__ W2f, bf16* __restrict__ W3t) {
  const int b = blockIdx.x, o = threadIdx.x;
  float vals[14];
  if (b < 49) {
    const int i = b;
    const size_t io = (size_t)i * 256 + o;
    const float spv = sp1[io];
#pragma unroll
    for (int r = 0; r < 13; ++r) vals[r] = c1[io * 13 + r] * spv;
    vals[13] = sb1[io];
    unsigned int* dst = (unsigned int*)(W1t + (size_t)o * 704 + i * 14);
#pragma unroll
    for (int d = 0; d < 7; ++d)
      dst[d] = (unsigned int)f2bf_bits(vals[2 * d]) |
               ((unsigned int)f2bf_bits(vals[2 * d + 1]) << 16);
  } else if (b == 49) {
    unsigned int* dst = (unsigned int*)(W1t + (size_t)o * 704 + 686);
#pragma unroll
    for (int d = 0; d < 9; ++d) dst[d] = 0u;  // K-pad 686..703
  } else if (b < 306) {
    const int i = b - 50;
    const size_t io = (size_t)i * 256 + o;
    const float spv = sp2[io];
#pragma unroll
    for (int r = 0; r < 13; ++r) vals[r] = c2[io * 13 + r] * spv;
    vals[13] = sb2[io];
    const int ntg = o >> 4, lr = o & 15;
#pragma unroll
    for (int d = 0; d < 7; ++d) {
      const int k2 = i * 14 + 2 * d;
      const int kc = k2 / 224, rem = k2 % 224;
      const int ks = rem / 32, r2 = rem % 32, quad = r2 / 8, el = r2 % 8;
      const size_t off = ((size_t)((kc * 7 + ks) * 16 + ntg)) * 512 + lr * 32 + quad * 8 + el;
      *(unsigned int*)(W2f + off) = (unsigned int)f2bf_bits(vals[2 * d]) |
                                    ((unsigned int)f2bf_bits(vals[2 * d + 1]) << 16);
    }
  } else {
    const int i = b - 306;
    if (o < 10) {
      const size_t io = (size_t)i * 10 + o;
      const float spv = sp3[io];
#pragma unroll
      for (int r = 0; r < 13; ++r) vals[r] = c3[io * 13 + r] * spv;
      vals[13] = sb3[io];
      unsigned int* dst = (unsigned int*)(W3t + (size_t)o * 3584 + i * 14);
#pragma unroll
      for (int d = 0; d < 7; ++d)
        dst[d] = (unsigned int)f2bf_bits(vals[2 * d]) |
                 ((unsigned int)f2bf_bits(vals[2 * d + 1]) << 16);
    } else if (o < 16) {
      unsigned int* dst = (unsigned int*)(W3t + (size_t)o * 3584 + i * 14);
#pragma unroll
      for (int d = 0; d < 7; ++d) dst[d] = 0u;  // N-pad rows 10..15
    }
  }
}

// One block per image: 4x4 avg-pool 28x28 -> 49, basis+mish -> A1 row (704 bf16).
__global__ __launch_bounds__(256) void pool_basis1(const float* __restrict__ x,
                                                   bf16* __restrict__ A1) {
  __shared__ __align__(16) float xs[784];
  __shared__ __align__(16) bf16 arow[704];
  const int b = blockIdx.x, t = threadIdx.x;
  if (t < 196) *(float4*)(&xs[t * 4]) = *(const float4*)(x + (size_t)b * 784 + t * 4);
  __syncthreads();
  if (t < 49) {
    const int oh = t / 7, ow = t % 7;
    float s = 0.f;
#pragma unroll
    for (int r = 0; r < 4; ++r)
#pragma unroll
      for (int c = 0; c < 4; ++c) s += xs[(oh * 4 + r) * 28 + ow * 4 + c];
    kan_feats28(&arow[t * 14], s * (1.0f / 16.0f));
  } else if (t < 67) {
    arow[686 + (t - 49)] = __float2bfloat16(0.0f);  // K pad 686..703
  }
  __syncthreads();
  if (t < 88) ((uint4*)((char*)A1 + (size_t)b * 1408))[t] = ((const uint4*)arow)[t];
}

// Layer-1 GEMM (K=704, BK=64, XOR-swizzled LDS — proven R3 structure), bias added.
__global__ __launch_bounds__(256) void gemm1s(
    const bf16* __restrict__ A, const bf16* __restrict__ Wt,
    const float* __restrict__ bias, float* __restrict__ H) {
  constexpr int K = 704;
  __shared__ __align__(16) bf16 As[64 * 64];
  __shared__ __align__(16) bf16 Bs[64 * 64];
  const int t = threadIdx.x;
  const int wv = t >> 6, lane = t & 63, quad = lane >> 4, lr = lane & 15;
  const int n0 = blockIdx.x * 64;
  const int m0 = blockIdx.y * 64;
  const int srow0 = lane >> 3;
  const int cg = (lane & 7) ^ srow0;
  const bf16* gA0 = A + (size_t)(m0 + 8 * wv + srow0) * K + cg * 8;
  const bf16* gA1 = A + (size_t)(m0 + 32 + 8 * wv + srow0) * K + cg * 8;
  const bf16* gB0 = Wt + (size_t)(n0 + 8 * wv + srow0) * K + cg * 8;
  const bf16* gB1 = Wt + (size_t)(n0 + 32 + 8 * wv + srow0) * K + cg * 8;
  char* const lA = (char*)As + wv * 1024;
  char* const lB = (char*)Bs + wv * 1024;
  const int wm = (wv & 1) * 32, wn = (wv >> 1) * 32;
  const int swz = lr & 7;
  f32x4_t acc00 = {0.f, 0.f, 0.f, 0.f}, acc01 = acc00, acc10 = acc00, acc11 = acc00;
  for (int k0 = 0; k0 < K; k0 += 64) {
    gld_lds16(gA0 + k0, lA);
    gld_lds16(gA1 + k0, lA + 4096);
    gld_lds16(gB0 + k0, lB);
    gld_lds16(gB1 + k0, lB + 4096);
    __syncthreads();
#pragma unroll
    for (int s = 0; s < 2; ++s) {
      const int co = ((s * 4 + quad) ^ swz) * 16;
      bf16x8_t a0 = *(const bf16x8_t*)((char*)As + (wm + lr) * 128 + co);
      bf16x8_t a1 = *(const bf16x8_t*)((char*)As + (wm + 16 + lr) * 128 + co);
      bf16x8_t b0 = *(const bf16x8_t*)((char*)Bs + (wn + lr) * 128 + co);
      bf16x8_t b1 = *(const bf16x8_t*)((char*)Bs + (wn + 16 + lr) * 128 + co);
      acc00 = __builtin_amdgcn_mfma_f32_16x16x32_bf16(a0, b0, acc00, 0, 0, 0);
      acc01 = __builtin_amdgcn_mfma_f32_16x16x32_bf16(a0, b1, acc01, 0, 0, 0);
      acc10 = __builtin_amdgcn_mfma_f32_16x16x32_bf16(a1, b0, acc10, 0, 0, 0);
      acc11 = __builtin_amdgcn_mfma_f32_16x16x32_bf16(a1, b1, acc11, 0, 0, 0);
    }
    __syncthreads();
  }
  const int cb = n0 + wn + lr;
  const float bn0 = bias[cb], bn1 = bias[cb + 16];
#pragma unroll
  for (int r = 0; r < 4; ++r) {
    const size_t row = (size_t)(m0 + wm + quad * 4 + r);
    H[row * 256 + cb] = acc00[r] + bn0;
    H[row * 256 + cb + 16] = acc01[r] + bn1;
    H[(row + 16) * 256 + cb] = acc10[r] + bn0;
    H[(row + 16) * 256 + cb + 16] = acc11[r] + bn1;
  }
}

// Fused KAN layer 2: grid (2, 128). Block = 64 rows x 128 cols; wave w owns
// cols [nb*128 + w*32, +32). Feats computed once per (block, K-chunk) into LDS
// A-tile (stride 464B, bank-balanced). B fragments loaded register-direct from
// frag-major W2f (L2-resident, fully coalesced dwordx4).
__global__ __launch_bounds__(256, 2) void kan_gemm2(
    const float* __restrict__ Hin, const bf16* __restrict__ W2f,
    const float* __restrict__ bias, float* __restrict__ Hout) {
  __shared__ __align__(16) bf16 As[64 * 232];  // 29696 B
  const int t = threadIdx.x;
  const int w = t >> 6, lane = t & 63, quad = lane >> 4, lr = lane & 15;
  const int m0 = blockIdx.y * 64;
  const int nb = blockIdx.x;
  const int ntg0 = nb * 8 + w * 2;
  const int ej = t & 15, er0 = t >> 4;
  const int foff = lr * 32 + quad * 8;
  f32x4_t acc[4][2];
#pragma unroll
  for (int m = 0; m < 4; ++m)
#pragma unroll
    for (int l = 0; l < 2; ++l) acc[m][l] = (f32x4_t){0.f, 0.f, 0.f, 0.f};
  const float* hp = Hin + (size_t)(m0 + er0) * 256 + ej;
  for (int kc = 0; kc < 16; ++kc) {
#pragma unroll
    for (int e = 0; e < 4; ++e)
      kan_feats28(As + (er0 + 16 * e) * 232 + ej * 14, hp[e * 16 * 256 + kc * 16]);
    __syncthreads();
#pragma unroll
    for (int ks = 0; ks < 7; ++ks) {
      bf16x8_t b0 = *(const bf16x8_t*)(W2f + ((size_t)((kc * 7 + ks) * 16 + ntg0)) * 512 + foff);
      bf16x8_t b1 = *(const bf16x8_t*)(W2f + ((size_t)((kc * 7 + ks) * 16 + ntg0 + 1)) * 512 + foff);
#pragma unroll
      for (int m = 0; m < 4; ++m) {
        bf16x8_t a = *(const bf16x8_t*)(As + (m * 16 + lr) * 232 + ks * 32 + quad * 8);
        acc[m][0] = __builtin_amdgcn_mfma_f32_16x16x32_bf16(a, b0, acc[m][0], 0, 0, 0);
        acc[m][1] = __builtin_amdgcn_mfma_f32_16x16x32_bf16(a, b1, acc[m][1], 0, 0, 0);
      }
    }
    __syncthreads();
  }
  const int c0 = nb * 128 + w * 32 + lr;
  const float bn0 = bias[c0], bn1 = bias[c0 + 16];
#pragma unroll
  for (int m = 0; m < 4; ++m)
#pragma unroll
    for (int r = 0; r < 4; ++r) {
      const size_t row = (size_t)(m0 + m * 16 + quad * 4 + r);
      Hout[row * 256 + c0] = acc[m][0][r] + bn0;
      Hout[row * 256 + c0 + 16] = acc[m][1][r] + bn1;
    }
}

// Fused layer 3: M=64 tile, N=16 (10 real), split-K over blockIdx.y (4 x 4 chunks).
// partials [z][n][m] for coalesced reduction. Feats computed once per element.
__global__ __launch_bounds__(256) void kan_gemm3(
    const float* __restrict__ Hin, const bf16* __restrict__ Wt,
    float* __restrict__ part) {
  constexpr int K = 3584;
  __shared__ __align__(16) bf16 As[64 * 232];
  __shared__ __align__(16) bf16 Bs[16 * 256];
  const int t = threadIdx.x;
  const int wv = t >> 6, lane = t & 63, quad = lane >> 4, lr = lane & 15;
  const int m0 = blockIdx.x * 64;
  const int z = blockIdx.y;
  const int ej = t & 15, er0 = t >> 4;
  const int brow_sub = lane >> 5, bslot = lane & 31;
  f32x4_t acc = {0.f, 0.f, 0.f, 0.f};
  for (int kcl = 0; kcl < 4; ++kcl) {
    const int kc = z * 4 + kcl;
#pragma unroll
    for (int n = 0; n < 2; ++n) {
      const int row = wv * 4 + n * 2 + brow_sub;
      int c = bslot ^ (row & 7);
      if (c >= 28) c = 0;
      const bf16* src = Wt + (size_t)row * K + kc * 224 + c * 8;
      gld_lds16(src, (char*)Bs + (wv * 4 + n * 2) * 512);
    }
    const float* hp = Hin + (size_t)(m0 + er0) * 256 + kc * 16 + ej;
    bf16* arow = As + er0 * 232 + ej * 14;
#pragma unroll
    for (int e = 0; e < 4; ++e) kan_feats28(arow + e * 16 * 232, hp[e * 16 * 256]);
    __syncthreads();
#pragma unroll
    for (int ks = 0; ks < 7; ++ks) {
      const int coA = ks * 64 + quad * 16;
      const int sb = ((ks * 4 + quad) ^ (lr & 7)) * 16;
      bf16x8_t a = *(const bf16x8_t*)((const char*)As + (wv * 16 + lr) * 464 + coA);
      bf16x8_t b = *(const bf16x8_t*)((const char*)Bs + lr * 512 + sb);
      acc = __builtin_amdgcn_mfma_f32_16x16x32_bf16(a, b, acc, 0, 0, 0);
    }
    __syncthreads();
  }
#pragma unroll
  for (int r = 0; r < 4; ++r)
    part[(size_t)z * 131072 + (size_t)lr * 8192 + (m0 + wv * 16 + quad * 4 + r)] = acc[r];
}

// Reduce 4 split-K partials + bias, log_softmax over 10 classes.
__global__ __launch_bounds__(256) void lsm(const float* __restrict__ part,
                                           const float* __restrict__ b3,
                                           float* __restrict__ out) {
  const int row = blockIdx.x * 256 + threadIdx.x;
  float v[10];
#pragma unroll
  for (int o = 0; o < 10; ++o) {
    float s = b3[o];
#pragma unroll
    for (int kc = 0; kc < 4; ++kc) s += part[(size_t)kc * 131072 + (size_t)o * 8192 + row];
    v[o] = s;
  }
  float m = v[0];
#pragma unroll
  for (int o = 1; o < 10; ++o) m = fmaxf(m, v[o]);
  float se = 0.f;
#pragma unroll
  for (int o = 0; o < 10; ++o) se += expf(v[o] - m);
  const float l = m + logf(se);
#pragma unroll
  for (int o = 0; o < 10; ++o) out[(size_t)row * 10 + o] = v[o] - l;
}

extern "C" void kernel_launch(void* const* d_in, const int* in_sizes, int n_in,
                              void* d_out, int out_size, void* d_ws, size_t ws_size,
                              hipStream_t stream) {
  const float* x = (const float*)d_in[0];
  const float* coef1 = (const float*)d_in[1];
  const float* sb1 = (const float*)d_in[2];
  const float* sp1 = (const float*)d_in[3];
  const float* b1 = (const float*)d_in[4];
  const float* coef2 = (const float*)d_in[5];
  const float* sb2 = (const float*)d_in[6];
  const float* sp2 = (const float*)d_in[7];
  const float* b2 = (const float*)d_in[8];
  const float* coef3 = (const float*)d_in[9];
  const float* sb3 = (const float*)d_in[10];
  const float* sp3 = (const float*)d_in[11];
  const float* b3 = (const float*)d_in[12];
  float* out = (float*)d_out;

  char* ws = (char*)d_ws;
  size_t off = 0;
  bf16* A1 = (bf16*)(ws + off);    off += 11534336;  // 8192*704*2
  bf16* W1t = (bf16*)(ws + off);   off += 360448;    // 256*704*2
  bf16* W2f = (bf16*)(ws + off);   off += 1835008;   // 256*3584*2 (frag-major)
  bf16* W3t = (bf16*)(ws + off);   off += 114688;    // 16*3584*2
  float* H1 = (float*)(ws + off);  off += 8388608;   // 8192*256*4
  float* H2 = (float*)(ws + off);  off += 8388608;
  float* part = (float*)(ws + off); off += 2097152;  // 4*16*8192*4

  prep_all<<<562, 256, 0, stream>>>(coef1, sb1, sp1, coef2, sb2, sp2,
                                    coef3, sb3, sp3, W1t, W2f, W3t);
  pool_basis1<<<8192, 256, 0, stream>>>(x, A1);
  gemm1s<<<dim3(4, 128), 256, 0, stream>>>(A1, W1t, b1, H1);
  kan_gemm2<<<dim3(2, 128), 256, 0, stream>>>(H1, W2f, b2, H2);
  kan_gemm3<<<dim3(128, 4), 256, 0, stream>>>(H2, W3t, part);
  lsm<<<32, 256, 0, stream>>>(part, b3, out);
}

// Round 6
// 151.898 us; speedup vs baseline: 1.3275x; 1.2326x over previous
//
#include <hip/hip_runtime.h>
#include <hip/hip_bf16.h>

typedef __bf16 bf16x8_t __attribute__((ext_vector_type(8)));
typedef float f32x4_t __attribute__((ext_vector_type(4)));
using bf16 = __hip_bfloat16;

#define ASG __attribute__((address_space(1)))
#define ASL __attribute__((address_space(3)))

__device__ __forceinline__ void gld_lds16(const void* g, void* l) {
  // lane i of the wave lands at (wave-uniform lds base) + i*16 bytes; src is per-lane.
  __builtin_amdgcn_global_load_lds((ASG void*)const_cast<void*>(g),
                                   (ASL void*)l, 16, 0, 0);
}

__device__ __forceinline__ unsigned short f2bf_bits(float v) {
  __hip_bfloat16 h = __float2bfloat16(v);
  return *reinterpret_cast<unsigned short*>(&h);
}

// mish(x) = x*tanh(softplus(x)) = x*n/(n+2) with n = e^x*(e^x+2).
__device__ __forceinline__ float mish_f(float x) {
  float z = __expf(x);
  float n = z * (z + 2.0f);
  float m = x * n / (n + 2.0f);
  return (x > 10.0f) ? x : m;
}

// 13 cubic B-spline basis values (grid 10, k=3, [-2,2]) + mish -> 28B LDS region.
__device__ __forceinline__ void kan_feats28(bf16* dst, float x) {
  unsigned int* d32 = (unsigned int*)dst;
#pragma unroll
  for (int d = 0; d < 7; ++d) d32[d] = 0u;
  float t = (x + 3.2f) * 2.5f;
  if (t >= 0.0f && t < 16.0f) {
    float tf = floorf(t);
    int c = (int)tf;
    float u = t - tf;
    float um = 1.0f - u;
    float u2 = u * u, u3 = u2 * u;
    const float s6 = 1.0f / 6.0f;
    float w0 = um * um * um * s6;
    float w1 = (3.0f * u3 - 6.0f * u2 + 4.0f) * s6;
    float w2 = (-3.0f * u3 + 3.0f * u2 + 3.0f * u + 1.0f) * s6;
    float w3 = u3 * s6;
    int j0 = c - 3;
    if (j0 >= 0)               dst[j0]     = __float2bfloat16(w0);
    if (j0 >= -1 && j0 <= 11)  dst[j0 + 1] = __float2bfloat16(w1);
    if (j0 >= -2 && j0 <= 10)  dst[j0 + 2] = __float2bfloat16(w2);
    if (j0 <= 9)               dst[j0 + 3] = __float2bfloat16(w3);
  }
  dst[13] = __float2bfloat16(mish_f(x));
}

// Builds W1t (row-major K=704), W2f (MFMA-fragment-major), W3t (row-major).
__global__ __launch_bounds__(256) void prep_all(
    const float* __restrict__ c1, const float* __restrict__ sb1, const float* __restrict__ sp1,
    const float* __restrict__ c2, const float* __restrict__ sb2, const float* __restrict__ sp2,
    const float* __restrict__ c3, const float* __restrict__ sb3, const float* __restrict__ sp3,
    bf16* __restrict__ W1t, bf16* __restrict__ W2f, bf16* __restrict__ W3t) {
  const int b = blockIdx.x, o = threadIdx.x;
  float vals[14];
  if (b < 49) {
    const int i = b;
    const size_t io = (size_t)i * 256 + o;
    const float spv = sp1[io];
#pragma unroll
    for (int r = 0; r < 13; ++r) vals[r] = c1[io * 13 + r] * spv;
    vals[13] = sb1[io];
    unsigned int* dst = (unsigned int*)(W1t + (size_t)o * 704 + i * 14);
#pragma unroll
    for (int d = 0; d < 7; ++d)
      dst[d] = (unsigned int)f2bf_bits(vals[2 * d]) |
               ((unsigned int)f2bf_bits(vals[2 * d + 1]) << 16);
  } else if (b == 49) {
    unsigned int* dst = (unsigned int*)(W1t + (size_t)o * 704 + 686);
#pragma unroll
    for (int d = 0; d < 9; ++d) dst[d] = 0u;  // K-pad 686..703
  } else if (b < 306) {
    const int i = b - 50;
    const size_t io = (size_t)i * 256 + o;
    const float spv = sp2[io];
#pragma unroll
    for (int r = 0; r < 13; ++r) vals[r] = c2[io * 13 + r] * spv;
    vals[13] = sb2[io];
    const int ntg = o >> 4, lr = o & 15;
#pragma unroll
    for (int d = 0; d < 7; ++d) {
      const int k2 = i * 14 + 2 * d;
      const int kc = k2 / 224, rem = k2 % 224;
      const int ks = rem / 32, r2 = rem % 32, quad = r2 / 8, el = r2 % 8;
      const size_t off = ((size_t)((kc * 7 + ks) * 16 + ntg)) * 512 + lr * 32 + quad * 8 + el;
      *(unsigned int*)(W2f + off) = (unsigned int)f2bf_bits(vals[2 * d]) |
                                    ((unsigned int)f2bf_bits(vals[2 * d + 1]) << 16);
    }
  } else {
    const int i = b - 306;
    if (o < 10) {
      const size_t io = (size_t)i * 10 + o;
      const float spv = sp3[io];
#pragma unroll
      for (int r = 0; r < 13; ++r) vals[r] = c3[io * 13 + r] * spv;
      vals[13] = sb3[io];
      unsigned int* dst = (unsigned int*)(W3t + (size_t)o * 3584 + i * 14);
#pragma unroll
      for (int d = 0; d < 7; ++d)
        dst[d] = (unsigned int)f2bf_bits(vals[2 * d]) |
                 ((unsigned int)f2bf_bits(vals[2 * d + 1]) << 16);
    } else if (o < 16) {
      unsigned int* dst = (unsigned int*)(W3t + (size_t)o * 3584 + i * 14);
#pragma unroll
      for (int d = 0; d < 7; ++d) dst[d] = 0u;  // N-pad rows 10..15
    }
  }
}

// One block per image: 4x4 avg-pool 28x28 -> 49, basis+mish -> A1 row (704 bf16).
__global__ __launch_bounds__(256) void pool_basis1(const float* __restrict__ x,
                                                   bf16* __restrict__ A1) {
  __shared__ __align__(16) float xs[784];
  __shared__ __align__(16) bf16 arow[704];
  const int b = blockIdx.x, t = threadIdx.x;
  if (t < 196) *(float4*)(&xs[t * 4]) = *(const float4*)(x + (size_t)b * 784 + t * 4);
  __syncthreads();
  if (t < 49) {
    const int oh = t / 7, ow = t % 7;
    float s = 0.f;
#pragma unroll
    for (int r = 0; r < 4; ++r)
#pragma unroll
      for (int c = 0; c < 4; ++c) s += xs[(oh * 4 + r) * 28 + ow * 4 + c];
    kan_feats28(&arow[t * 14], s * (1.0f / 16.0f));
  } else if (t < 67) {
    arow[686 + (t - 49)] = __float2bfloat16(0.0f);  // K pad 686..703
  }
  __syncthreads();
  if (t < 88) ((uint4*)((char*)A1 + (size_t)b * 1408))[t] = ((const uint4*)arow)[t];
}

// Layer-1 GEMM (K=704, BK=64, XOR-swizzled LDS), bias added.
__global__ __launch_bounds__(256) void gemm1s(
    const bf16* __restrict__ A, const bf16* __restrict__ Wt,
    const float* __restrict__ bias, float* __restrict__ H) {
  constexpr int K = 704;
  __shared__ __align__(16) bf16 As[64 * 64];
  __shared__ __align__(16) bf16 Bs[64 * 64];
  const int t = threadIdx.x;
  const int wv = t >> 6, lane = t & 63, quad = lane >> 4, lr = lane & 15;
  const int n0 = blockIdx.x * 64;
  const int m0 = blockIdx.y * 64;
  const int srow0 = lane >> 3;
  const int cg = (lane & 7) ^ srow0;
  const bf16* gA0 = A + (size_t)(m0 + 8 * wv + srow0) * K + cg * 8;
  const bf16* gA1 = A + (size_t)(m0 + 32 + 8 * wv + srow0) * K + cg * 8;
  const bf16* gB0 = Wt + (size_t)(n0 + 8 * wv + srow0) * K + cg * 8;
  const bf16* gB1 = Wt + (size_t)(n0 + 32 + 8 * wv + srow0) * K + cg * 8;
  char* const lA = (char*)As + wv * 1024;
  char* const lB = (char*)Bs + wv * 1024;
  const int wm = (wv & 1) * 32, wn = (wv >> 1) * 32;
  const int swz = lr & 7;
  f32x4_t acc00 = {0.f, 0.f, 0.f, 0.f}, acc01 = acc00, acc10 = acc00, acc11 = acc00;
  for (int k0 = 0; k0 < K; k0 += 64) {
    gld_lds16(gA0 + k0, lA);
    gld_lds16(gA1 + k0, lA + 4096);
    gld_lds16(gB0 + k0, lB);
    gld_lds16(gB1 + k0, lB + 4096);
    __syncthreads();
#pragma unroll
    for (int s = 0; s < 2; ++s) {
      const int co = ((s * 4 + quad) ^ swz) * 16;
      bf16x8_t a0 = *(const bf16x8_t*)((char*)As + (wm + lr) * 128 + co);
      bf16x8_t a1 = *(const bf16x8_t*)((char*)As + (wm + 16 + lr) * 128 + co);
      bf16x8_t b0 = *(const bf16x8_t*)((char*)Bs + (wn + lr) * 128 + co);
      bf16x8_t b1 = *(const bf16x8_t*)((char*)Bs + (wn + 16 + lr) * 128 + co);
      acc00 = __builtin_amdgcn_mfma_f32_16x16x32_bf16(a0, b0, acc00, 0, 0, 0);
      acc01 = __builtin_amdgcn_mfma_f32_16x16x32_bf16(a0, b1, acc01, 0, 0, 0);
      acc10 = __builtin_amdgcn_mfma_f32_16x16x32_bf16(a1, b0, acc10, 0, 0, 0);
      acc11 = __builtin_amdgcn_mfma_f32_16x16x32_bf16(a1, b1, acc11, 0, 0, 0);
    }
    __syncthreads();
  }
  const int cb = n0 + wn + lr;
  const float bn0 = bias[cb], bn1 = bias[cb + 16];
#pragma unroll
  for (int r = 0; r < 4; ++r) {
    const size_t row = (size_t)(m0 + wm + quad * 4 + r);
    H[row * 256 + cb] = acc00[r] + bn0;
    H[row * 256 + cb + 16] = acc01[r] + bn1;
    H[(row + 16) * 256 + cb] = acc10[r] + bn0;
    H[(row + 16) * 256 + cb + 16] = acc11[r] + bn1;
  }
}

// Fused KAN layer 2, v3: grid (128 m-tiles, 4 k-splits) = 512 blocks (2/CU).
// Block = 64 rows x 256 cols over K-range z*896..+896 (4 chunks of 224).
// Wave w owns cols w*64..+63 (acc 4x4 frags = 64 VGPRs). Feats computed once
// globally (z partitions inputs), double-buffered in LDS; one barrier/chunk.
// B frags register-direct from frag-major W2f (L2-resident). Partials to Hp[z].
__global__ __launch_bounds__(256, 2) void kan_gemm2(
    const float* __restrict__ Hin, const bf16* __restrict__ W2f,
    float* __restrict__ Hp) {
  __shared__ __align__(16) bf16 As[2][64 * 232];  // 2 x 29696 B
  const int t = threadIdx.x;
  const int w = t >> 6, lane = t & 63, quad = lane >> 4, lr = lane & 15;
  const int m0 = blockIdx.x * 64;
  const int z = blockIdx.y;
  const int ej = t & 15, er0 = t >> 4;
  const int foff = lr * 32 + quad * 8;
  f32x4_t acc[4][4];
#pragma unroll
  for (int m = 0; m < 4; ++m)
#pragma unroll
    for (int n = 0; n < 4; ++n) acc[m][n] = (f32x4_t){0.f, 0.f, 0.f, 0.f};
  const float* hp = Hin + (size_t)(m0 + er0) * 256 + z * 64 + ej;
#pragma unroll
  for (int e = 0; e < 4; ++e)
    kan_feats28(As[0] + (er0 + 16 * e) * 232 + ej * 14, hp[e * 16 * 256]);
  for (int kcl = 0; kcl < 4; ++kcl) {
    __syncthreads();
    const bf16* cur = As[kcl & 1];
    bf16* nxt = As[(kcl & 1) ^ 1];
    const int kc = z * 4 + kcl;
#pragma unroll
    for (int ks = 0; ks < 7; ++ks) {
      const size_t fb = ((size_t)((kc * 7 + ks) * 16 + w * 4)) * 512 + foff;
      bf16x8_t b0 = *(const bf16x8_t*)(W2f + fb);
      bf16x8_t b1 = *(const bf16x8_t*)(W2f + fb + 512);
      bf16x8_t b2 = *(const bf16x8_t*)(W2f + fb + 1024);
      bf16x8_t b3 = *(const bf16x8_t*)(W2f + fb + 1536);
#pragma unroll
      for (int m = 0; m < 4; ++m) {
        bf16x8_t a = *(const bf16x8_t*)(cur + (m * 16 + lr) * 232 + ks * 32 + quad * 8);
        acc[m][0] = __builtin_amdgcn_mfma_f32_16x16x32_bf16(a, b0, acc[m][0], 0, 0, 0);
        acc[m][1] = __builtin_amdgcn_mfma_f32_16x16x32_bf16(a, b1, acc[m][1], 0, 0, 0);
        acc[m][2] = __builtin_amdgcn_mfma_f32_16x16x32_bf16(a, b2, acc[m][2], 0, 0, 0);
        acc[m][3] = __builtin_amdgcn_mfma_f32_16x16x32_bf16(a, b3, acc[m][3], 0, 0, 0);
      }
    }
    if (kcl < 3) {
#pragma unroll
      for (int e = 0; e < 4; ++e)
        kan_feats28(nxt + (er0 + 16 * e) * 232 + ej * 14,
                    hp[e * 16 * 256 + (kcl + 1) * 16]);
    }
  }
  float* Hpz = Hp + (size_t)z * (8192 * 256);
  const int c0 = w * 64 + lr;
#pragma unroll
  for (int m = 0; m < 4; ++m)
#pragma unroll
    for (int r = 0; r < 4; ++r) {
      const size_t row = (size_t)(m0 + m * 16 + quad * 4 + r);
#pragma unroll
      for (int n = 0; n < 4; ++n)
        Hpz[row * 256 + c0 + n * 16] = acc[m][n][r];
    }
}

// Fused layer 3: reduces the 4 layer-2 partials (+b2) inline in the feats read.
// M=64 tile, N=16 (10 real), split-K over blockIdx.y (4 x 4 chunks).
__global__ __launch_bounds__(256) void kan_gemm3(
    const float* __restrict__ Hp, const float* __restrict__ b2,
    const bf16* __restrict__ Wt, float* __restrict__ part) {
  constexpr int K = 3584;
  __shared__ __align__(16) bf16 As[64 * 232];
  __shared__ __align__(16) bf16 Bs[16 * 256];
  const int t = threadIdx.x;
  const int wv = t >> 6, lane = t & 63, quad = lane >> 4, lr = lane & 15;
  const int m0 = blockIdx.x * 64;
  const int z = blockIdx.y;
  const int ej = t & 15, er0 = t >> 4;
  const int brow_sub = lane >> 5, bslot = lane & 31;
  f32x4_t acc = {0.f, 0.f, 0.f, 0.f};
  for (int kcl = 0; kcl < 4; ++kcl) {
    const int kc = z * 4 + kcl;
#pragma unroll
    for (int n = 0; n < 2; ++n) {
      const int row = wv * 4 + n * 2 + brow_sub;
      int c = bslot ^ (row & 7);
      if (c >= 28) c = 0;
      const bf16* src = Wt + (size_t)row * K + kc * 224 + c * 8;
      gld_lds16(src, (char*)Bs + (wv * 4 + n * 2) * 512);
    }
    const float bc = b2[kc * 16 + ej];
    const float* hp = Hp + (size_t)(m0 + er0) * 256 + kc * 16 + ej;
    bf16* arow = As + er0 * 232 + ej * 14;
#pragma unroll
    for (int e = 0; e < 4; ++e) {
      const size_t idx = (size_t)e * 16 * 256;
      float h = hp[idx] + hp[idx + 2097152] + hp[idx + 4194304] + hp[idx + 6291456] + bc;
      kan_feats28(arow + e * 16 * 232, h);
    }
    __syncthreads();
#pragma unroll
    for (int ks = 0; ks < 7; ++ks) {
      const int coA = ks * 64 + quad * 16;
      const int sb = ((ks * 4 + quad) ^ (lr & 7)) * 16;
      bf16x8_t a = *(const bf16x8_t*)((const char*)As + (wv * 16 + lr) * 464 + coA);
      bf16x8_t b = *(const bf16x8_t*)((const char*)Bs + lr * 512 + sb);
      acc = __builtin_amdgcn_mfma_f32_16x16x32_bf16(a, b, acc, 0, 0, 0);
    }
    __syncthreads();
  }
#pragma unroll
  for (int r = 0; r < 4; ++r)
    part[(size_t)z * 131072 + (size_t)lr * 8192 + (m0 + wv * 16 + quad * 4 + r)] = acc[r];
}

// Reduce 4 split-K partials + bias, log_softmax over 10 classes.
__global__ __launch_bounds__(256) void lsm(const float* __restrict__ part,
                                           const float* __restrict__ b3,
                                           float* __restrict__ out) {
  const int row = blockIdx.x * 256 + threadIdx.x;
  float v[10];
#pragma unroll
  for (int o = 0; o < 10; ++o) {
    float s = b3[o];
#pragma unroll
    for (int kc = 0; kc < 4; ++kc) s += part[(size_t)kc * 131072 + (size_t)o * 8192 + row];
    v[o] = s;
  }
  float m = v[0];
#pragma unroll
  for (int o = 1; o < 10; ++o) m = fmaxf(m, v[o]);
  float se = 0.f;
#pragma unroll
  for (int o = 0; o < 10; ++o) se += expf(v[o] - m);
  const float l = m + logf(se);
#pragma unroll
  for (int o = 0; o < 10; ++o) out[(size_t)row * 10 + o] = v[o] - l;
}

extern "C" void kernel_launch(void* const* d_in, const int* in_sizes, int n_in,
                              void* d_out, int out_size, void* d_ws, size_t ws_size,
                              hipStream_t stream) {
  const float* x = (const float*)d_in[0];
  const float* coef1 = (const float*)d_in[1];
  const float* sb1 = (const float*)d_in[2];
  const float* sp1 = (const float*)d_in[3];
  const float* b1 = (const float*)d_in[4];
  const float* coef2 = (const float*)d_in[5];
  const float* sb2 = (const float*)d_in[6];
  const float* sp2 = (const float*)d_in[7];
  const float* b2 = (const float*)d_in[8];
  const float* coef3 = (const float*)d_in[9];
  const float* sb3 = (const float*)d_in[10];
  const float* sp3 = (const float*)d_in[11];
  const float* b3 = (const float*)d_in[12];
  float* out = (float*)d_out;

  char* ws = (char*)d_ws;
  size_t off = 0;
  bf16* A1 = (bf16*)(ws + off);    off += 11534336;  // 8192*704*2
  bf16* W1t = (bf16*)(ws + off);   off += 360448;    // 256*704*2
  bf16* W2f = (bf16*)(ws + off);   off += 1835008;   // 256*3584*2 (frag-major)
  bf16* W3t = (bf16*)(ws + off);   off += 114688;    // 16*3584*2
  float* H1 = (float*)(ws + off);  off += 8388608;   // 8192*256*4
  float* Hp = (float*)(ws + off);  off += 33554432;  // 4 x 8192*256*4 (L2 partials)
  float* part = (float*)(ws + off); off += 2097152;  // 4*16*8192*4

  prep_all<<<562, 256, 0, stream>>>(coef1, sb1, sp1, coef2, sb2, sp2,
                                    coef3, sb3, sp3, W1t, W2f, W3t);
  pool_basis1<<<8192, 256, 0, stream>>>(x, A1);
  gemm1s<<<dim3(4, 128), 256, 0, stream>>>(A1, W1t, b1, H1);
  kan_gemm2<<<dim3(128, 4), 256, 0, stream>>>(H1, W2f, Hp);
  kan_gemm3<<<dim3(128, 4), 256, 0, stream>>>(Hp, b2, W3t, part);
  lsm<<<32, 256, 0, stream>>>(part, b3, out);
}

// Round 7
// 146.202 us; speedup vs baseline: 1.3792x; 1.0390x over previous
//
#include <hip/hip_runtime.h>
#include <hip/hip_bf16.h>

typedef __bf16 bf16x8_t __attribute__((ext_vector_type(8)));
typedef float f32x4_t __attribute__((ext_vector_type(4)));
using bf16 = __hip_bfloat16;

#define ASG __attribute__((address_space(1)))
#define ASL __attribute__((address_space(3)))

__device__ __forceinline__ void gld_lds16(const void* g, void* l) {
  // lane i of the wave lands at (wave-uniform lds base) + i*16 bytes; src is per-lane.
  __builtin_amdgcn_global_load_lds((ASG void*)const_cast<void*>(g),
                                   (ASL void*)l, 16, 0, 0);
}

__device__ __forceinline__ unsigned short f2bf_bits(float v) {
  __hip_bfloat16 h = __float2bfloat16(v);
  return *reinterpret_cast<unsigned short*>(&h);
}

// mish(x) = x*tanh(softplus(x)) = x*n/(n+2) with n = e^x*(e^x+2).
__device__ __forceinline__ float mish_f(float x) {
  float z = __expf(x);
  float n = z * (z + 2.0f);
  float m = x * n / (n + 2.0f);
  return (x > 10.0f) ? x : m;
}

// 13 cubic B-spline basis values (grid 10, k=3, [-2,2]) + mish -> 28B LDS region.
__device__ __forceinline__ void kan_feats28(bf16* dst, float x) {
  unsigned int* d32 = (unsigned int*)dst;
#pragma unroll
  for (int d = 0; d < 7; ++d) d32[d] = 0u;
  float t = (x + 3.2f) * 2.5f;
  if (t >= 0.0f && t < 16.0f) {
    float tf = floorf(t);
    int c = (int)tf;
    float u = t - tf;
    float um = 1.0f - u;
    float u2 = u * u, u3 = u2 * u;
    const float s6 = 1.0f / 6.0f;
    float w0 = um * um * um * s6;
    float w1 = (3.0f * u3 - 6.0f * u2 + 4.0f) * s6;
    float w2 = (-3.0f * u3 + 3.0f * u2 + 3.0f * u + 1.0f) * s6;
    float w3 = u3 * s6;
    int j0 = c - 3;
    if (j0 >= 0)               dst[j0]     = __float2bfloat16(w0);
    if (j0 >= -1 && j0 <= 11)  dst[j0 + 1] = __float2bfloat16(w1);
    if (j0 >= -2 && j0 <= 10)  dst[j0 + 2] = __float2bfloat16(w2);
    if (j0 <= 9)               dst[j0 + 3] = __float2bfloat16(w3);
  }
  dst[13] = __float2bfloat16(mish_f(x));
}

// Builds W1t (row-major K=704), W2f (MFMA-fragment-major), W3t (row-major).
__global__ __launch_bounds__(256) void prep_all(
    const float* __restrict__ c1, const float* __restrict__ sb1, const float* __restrict__ sp1,
    const float* __restrict__ c2, const float* __restrict__ sb2, const float* __restrict__ sp2,
    const float* __restrict__ c3, const float* __restrict__ sb3, const float* __restrict__ sp3,
    bf16* __restrict__ W1t, bf16* __restrict__ W2f, bf16* __restrict__ W3t) {
  const int b = blockIdx.x, o = threadIdx.x;
  float vals[14];
  if (b < 49) {
    const int i = b;
    const size_t io = (size_t)i * 256 + o;
    const float spv = sp1[io];
#pragma unroll
    for (int r = 0; r < 13; ++r) vals[r] = c1[io * 13 + r] * spv;
    vals[13] = sb1[io];
    unsigned int* dst = (unsigned int*)(W1t + (size_t)o * 704 + i * 14);
#pragma unroll
    for (int d = 0; d < 7; ++d)
      dst[d] = (unsigned int)f2bf_bits(vals[2 * d]) |
               ((unsigned int)f2bf_bits(vals[2 * d + 1]) << 16);
  } else if (b == 49) {
    unsigned int* dst = (unsigned int*)(W1t + (size_t)o * 704 + 686);
#pragma unroll
    for (int d = 0; d < 9; ++d) dst[d] = 0u;  // K-pad 686..703
  } else if (b < 306) {
    const int i = b - 50;
    const size_t io = (size_t)i * 256 + o;
    const float spv = sp2[io];
#pragma unroll
    for (int r = 0; r < 13; ++r) vals[r] = c2[io * 13 + r] * spv;
    vals[13] = sb2[io];
    const int ntg = o >> 4, lr = o & 15;
#pragma unroll
    for (int d = 0; d < 7; ++d) {
      const int k2 = i * 14 + 2 * d;
      const int kc = k2 / 224, rem = k2 % 224;
      const int ks = rem / 32, r2 = rem % 32, quad = r2 / 8, el = r2 % 8;
      const size_t off = ((size_t)((kc * 7 + ks) * 16 + ntg)) * 512 + lr * 32 + quad * 8 + el;
      *(unsigned int*)(W2f + off) = (unsigned int)f2bf_bits(vals[2 * d]) |
                                    ((unsigned int)f2bf_bits(vals[2 * d + 1]) << 16);
    }
  } else {
    const int i = b - 306;
    if (o < 10) {
      const size_t io = (size_t)i * 10 + o;
      const float spv = sp3[io];
#pragma unroll
      for (int r = 0; r < 13; ++r) vals[r] = c3[io * 13 + r] * spv;
      vals[13] = sb3[io];
      unsigned int* dst = (unsigned int*)(W3t + (size_t)o * 3584 + i * 14);
#pragma unroll
      for (int d = 0; d < 7; ++d)
        dst[d] = (unsigned int)f2bf_bits(vals[2 * d]) |
                 ((unsigned int)f2bf_bits(vals[2 * d + 1]) << 16);
    } else if (o < 16) {
      unsigned int* dst = (unsigned int*)(W3t + (size_t)o * 3584 + i * 14);
#pragma unroll
      for (int d = 0; d < 7; ++d) dst[d] = 0u;  // N-pad rows 10..15
    }
  }
}

// 4 images per block: 4x4 avg-pool 28x28 -> 49, basis+mish -> A1 rows (704 bf16).
__global__ __launch_bounds__(256) void pool_basis1(const float* __restrict__ x,
                                                   bf16* __restrict__ A1) {
  __shared__ __align__(16) float xs[3136];
  __shared__ __align__(16) bf16 arow[4 * 704];
  const int b4 = blockIdx.x * 4, t = threadIdx.x;
  const float4* xsrc = (const float4*)(x + (size_t)b4 * 784);
  float4* xd = (float4*)xs;
#pragma unroll
  for (int l = t; l < 784; l += 256) xd[l] = xsrc[l];
  __syncthreads();
  if (t < 196) {
    const int img = t / 49, p = t - img * 49;
    const int oh = p / 7, ow = p - oh * 7;
    const float* xi = xs + img * 784;
    float s = 0.f;
#pragma unroll
    for (int r = 0; r < 4; ++r)
#pragma unroll
      for (int c = 0; c < 4; ++c) s += xi[(oh * 4 + r) * 28 + ow * 4 + c];
    kan_feats28(&arow[img * 704 + p * 14], s * (1.0f / 16.0f));
  } else if (t < 232) {
    const int q = t - 196;  // 36 threads zero 4 pads of 9 dwords
    const int img = q / 9, d = q - img * 9;
    ((unsigned int*)(arow + img * 704 + 686))[d] = 0u;
  }
  __syncthreads();
  uint4* dst = (uint4*)(A1 + (size_t)b4 * 704);
  const uint4* src = (const uint4*)arow;
#pragma unroll
  for (int l = t; l < 352; l += 256) dst[l] = src[l];
}

// Layer-1 GEMM (K=704, BK=64, XOR-swizzled LDS), bias added.
__global__ __launch_bounds__(256) void gemm1s(
    const bf16* __restrict__ A, const bf16* __restrict__ Wt,
    const float* __restrict__ bias, float* __restrict__ H) {
  constexpr int K = 704;
  __shared__ __align__(16) bf16 As[64 * 64];
  __shared__ __align__(16) bf16 Bs[64 * 64];
  const int t = threadIdx.x;
  const int wv = t >> 6, lane = t & 63, quad = lane >> 4, lr = lane & 15;
  const int n0 = blockIdx.x * 64;
  const int m0 = blockIdx.y * 64;
  const int srow0 = lane >> 3;
  const int cg = (lane & 7) ^ srow0;
  const bf16* gA0 = A + (size_t)(m0 + 8 * wv + srow0) * K + cg * 8;
  const bf16* gA1 = A + (size_t)(m0 + 32 + 8 * wv + srow0) * K + cg * 8;
  const bf16* gB0 = Wt + (size_t)(n0 + 8 * wv + srow0) * K + cg * 8;
  const bf16* gB1 = Wt + (size_t)(n0 + 32 + 8 * wv + srow0) * K + cg * 8;
  char* const lA = (char*)As + wv * 1024;
  char* const lB = (char*)Bs + wv * 1024;
  const int wm = (wv & 1) * 32, wn = (wv >> 1) * 32;
  const int swz = lr & 7;
  f32x4_t acc00 = {0.f, 0.f, 0.f, 0.f}, acc01 = acc00, acc10 = acc00, acc11 = acc00;
  for (int k0 = 0; k0 < K; k0 += 64) {
    gld_lds16(gA0 + k0, lA);
    gld_lds16(gA1 + k0, lA + 4096);
    gld_lds16(gB0 + k0, lB);
    gld_lds16(gB1 + k0, lB + 4096);
    __syncthreads();
#pragma unroll
    for (int s = 0; s < 2; ++s) {
      const int co = ((s * 4 + quad) ^ swz) * 16;
      bf16x8_t a0 = *(const bf16x8_t*)((char*)As + (wm + lr) * 128 + co);
      bf16x8_t a1 = *(const bf16x8_t*)((char*)As + (wm + 16 + lr) * 128 + co);
      bf16x8_t b0 = *(const bf16x8_t*)((char*)Bs + (wn + lr) * 128 + co);
      bf16x8_t b1 = *(const bf16x8_t*)((char*)Bs + (wn + 16 + lr) * 128 + co);
      acc00 = __builtin_amdgcn_mfma_f32_16x16x32_bf16(a0, b0, acc00, 0, 0, 0);
      acc01 = __builtin_amdgcn_mfma_f32_16x16x32_bf16(a0, b1, acc01, 0, 0, 0);
      acc10 = __builtin_amdgcn_mfma_f32_16x16x32_bf16(a1, b0, acc10, 0, 0, 0);
      acc11 = __builtin_amdgcn_mfma_f32_16x16x32_bf16(a1, b1, acc11, 0, 0, 0);
    }
    __syncthreads();
  }
  const int cb = n0 + wn + lr;
  const float bn0 = bias[cb], bn1 = bias[cb + 16];
#pragma unroll
  for (int r = 0; r < 4; ++r) {
    const size_t row = (size_t)(m0 + wm + quad * 4 + r);
    H[row * 256 + cb] = acc00[r] + bn0;
    H[row * 256 + cb + 16] = acc01[r] + bn1;
    H[(row + 16) * 256 + cb] = acc10[r] + bn0;
    H[(row + 16) * 256 + cb + 16] = acc11[r] + bn1;
  }
}

// Fused KAN layer 2, v4: 512-thr blocks, grid (128 m, 4 z) = 512 blocks (2/CU,
// 4 waves/SIMD). Block = 64 rows x 256 cols x K-range z*896..+896. Wave w owns
// cols w*32..+31 (acc 4x2 frags = 32 VGPRs). Feats once globally, dbuf LDS,
// one barrier/chunk. B frags register-direct from frag-major W2f with explicit
// 2-deep prefetch pipeline (3 live pairs). Partials to Hp[z].
__global__ __launch_bounds__(512, 4) void kan_gemm2(
    const float* __restrict__ Hin, const bf16* __restrict__ W2f,
    float* __restrict__ Hp) {
  __shared__ __align__(16) bf16 As[2][64 * 232];  // 2 x 29696 B
  const int t = threadIdx.x;
  const int w = t >> 6, lane = t & 63, quad = lane >> 4, lr = lane & 15;
  const int m0 = blockIdx.x * 64;
  const int z = blockIdx.y;
  const int ej = t & 15, er0 = (t >> 4) & 31;
  const int foff = lr * 32 + quad * 8;
  f32x4_t acc[4][2];
#pragma unroll
  for (int m = 0; m < 4; ++m) {
    acc[m][0] = (f32x4_t){0.f, 0.f, 0.f, 0.f};
    acc[m][1] = (f32x4_t){0.f, 0.f, 0.f, 0.f};
  }
  const float* hp = Hin + (size_t)(m0 + er0) * 256 + z * 64 + ej;
  // feats for chunk 0
  kan_feats28(As[0] + er0 * 232 + ej * 14, hp[0]);
  kan_feats28(As[0] + (er0 + 32) * 232 + ej * 14, hp[32 * 256]);
  // B pipeline: frag stride per K-step = 16 frags = 8192 elements
  size_t fb = ((size_t)(z * 28 * 16 + w * 2)) * 512 + foff;
  bf16x8_t bA0 = *(const bf16x8_t*)(W2f + fb);
  bf16x8_t bA1 = *(const bf16x8_t*)(W2f + fb + 512);
  bf16x8_t bB0 = *(const bf16x8_t*)(W2f + fb + 8192);
  bf16x8_t bB1 = *(const bf16x8_t*)(W2f + fb + 8192 + 512);
  fb += 2 * 8192;
#pragma unroll
  for (int kcl = 0; kcl < 4; ++kcl) {
    __syncthreads();
    const bf16* cur = As[kcl & 1];
    bf16* nxt = As[(kcl & 1) ^ 1];
#pragma unroll
    for (int ks = 0; ks < 7; ++ks) {
      bf16x8_t bN0, bN1;
      if (kcl * 7 + ks < 26) {
        bN0 = *(const bf16x8_t*)(W2f + fb);
        bN1 = *(const bf16x8_t*)(W2f + fb + 512);
      } else {
        bN0 = bB0; bN1 = bB1;
      }
#pragma unroll
      for (int m = 0; m < 4; ++m) {
        bf16x8_t a = *(const bf16x8_t*)(cur + (m * 16 + lr) * 232 + ks * 32 + quad * 8);
        acc[m][0] = __builtin_amdgcn_mfma_f32_16x16x32_bf16(a, bA0, acc[m][0], 0, 0, 0);
        acc[m][1] = __builtin_amdgcn_mfma_f32_16x16x32_bf16(a, bA1, acc[m][1], 0, 0, 0);
      }
      bA0 = bB0; bA1 = bB1; bB0 = bN0; bB1 = bN1;
      fb += 8192;
    }
    if (kcl < 3) {
      kan_feats28(nxt + er0 * 232 + ej * 14, hp[(kcl + 1) * 16]);
      kan_feats28(nxt + (er0 + 32) * 232 + ej * 14, hp[32 * 256 + (kcl + 1) * 16]);
    }
  }
  float* Hpz = Hp + (size_t)z * (8192 * 256);
  const int c0 = w * 32 + lr;
#pragma unroll
  for (int m = 0; m < 4; ++m)
#pragma unroll
    for (int r = 0; r < 4; ++r) {
      const size_t row = (size_t)(m0 + m * 16 + quad * 4 + r);
      Hpz[row * 256 + c0] = acc[m][0][r];
      Hpz[row * 256 + c0 + 16] = acc[m][1][r];
    }
}

// Fused layer 3: reduces the 4 layer-2 partials (+b2) inline in the feats read.
// M=64 tile, N=16 (10 real), split-K over blockIdx.y (8 x 2 chunks) -> 4 blk/CU.
__global__ __launch_bounds__(256) void kan_gemm3(
    const float* __restrict__ Hp, const float* __restrict__ b2,
    const bf16* __restrict__ Wt, float* __restrict__ part) {
  constexpr int K = 3584;
  __shared__ __align__(16) bf16 As[64 * 232];
  __shared__ __align__(16) bf16 Bs[16 * 256];
  const int t = threadIdx.x;
  const int wv = t >> 6, lane = t & 63, quad = lane >> 4, lr = lane & 15;
  const int m0 = blockIdx.x * 64;
  const int z = blockIdx.y;
  const int ej = t & 15, er0 = t >> 4;
  const int brow_sub = lane >> 5, bslot = lane & 31;
  f32x4_t acc = {0.f, 0.f, 0.f, 0.f};
  for (int kcl = 0; kcl < 2; ++kcl) {
    const int kc = z * 2 + kcl;
#pragma unroll
    for (int n = 0; n < 2; ++n) {
      const int row = wv * 4 + n * 2 + brow_sub;
      int c = bslot ^ (row & 7);
      if (c >= 28) c = 0;
      const bf16* src = Wt + (size_t)row * K + kc * 224 + c * 8;
      gld_lds16(src, (char*)Bs + (wv * 4 + n * 2) * 512);
    }
    const float bc = b2[kc * 16 + ej];
    const float* hp = Hp + (size_t)(m0 + er0) * 256 + kc * 16 + ej;
    bf16* arow = As + er0 * 232 + ej * 14;
#pragma unroll
    for (int e = 0; e < 4; ++e) {
      const size_t idx = (size_t)e * 16 * 256;
      float h = hp[idx] + hp[idx + 2097152] + hp[idx + 4194304] + hp[idx + 6291456] + bc;
      kan_feats28(arow + e * 16 * 232, h);
    }
    __syncthreads();
#pragma unroll
    for (int ks = 0; ks < 7; ++ks) {
      const int coA = ks * 64 + quad * 16;
      const int sb = ((ks * 4 + quad) ^ (lr & 7)) * 16;
      bf16x8_t a = *(const bf16x8_t*)((const char*)As + (wv * 16 + lr) * 464 + coA);
      bf16x8_t b = *(const bf16x8_t*)((const char*)Bs + lr * 512 + sb);
      acc = __builtin_amdgcn_mfma_f32_16x16x32_bf16(a, b, acc, 0, 0, 0);
    }
    __syncthreads();
  }
#pragma unroll
  for (int r = 0; r < 4; ++r)
    part[(size_t)z * 131072 + (size_t)lr * 8192 + (m0 + wv * 16 + quad * 4 + r)] = acc[r];
}

// Reduce 8 split-K partials + bias, log_softmax over 10 classes.
__global__ __launch_bounds__(256) void lsm(const float* __restrict__ part,
                                           const float* __restrict__ b3,
                                           float* __restrict__ out) {
  const int row = blockIdx.x * 256 + threadIdx.x;
  float v[10];
#pragma unroll
  for (int o = 0; o < 10; ++o) {
    float s = b3[o];
#pragma unroll
    for (int kc = 0; kc < 8; ++kc) s += part[(size_t)kc * 131072 + (size_t)o * 8192 + row];
    v[o] = s;
  }
  float m = v[0];
#pragma unroll
  for (int o = 1; o < 10; ++o) m = fmaxf(m, v[o]);
  float se = 0.f;
#pragma unroll
  for (int o = 0; o < 10; ++o) se += expf(v[o] - m);
  const float l = m + logf(se);
#pragma unroll
  for (int o = 0; o < 10; ++o) out[(size_t)row * 10 + o] = v[o] - l;
}

extern "C" void kernel_launch(void* const* d_in, const int* in_sizes, int n_in,
                              void* d_out, int out_size, void* d_ws, size_t ws_size,
                              hipStream_t stream) {
  const float* x = (const float*)d_in[0];
  const float* coef1 = (const float*)d_in[1];
  const float* sb1 = (const float*)d_in[2];
  const float* sp1 = (const float*)d_in[3];
  const float* b1 = (const float*)d_in[4];
  const float* coef2 = (const float*)d_in[5];
  const float* sb2 = (const float*)d_in[6];
  const float* sp2 = (const float*)d_in[7];
  const float* b2 = (const float*)d_in[8];
  const float* coef3 = (const float*)d_in[9];
  const float* sb3 = (const float*)d_in[10];
  const float* sp3 = (const float*)d_in[11];
  const float* b3 = (const float*)d_in[12];
  float* out = (float*)d_out;

  char* ws = (char*)d_ws;
  size_t off = 0;
  bf16* A1 = (bf16*)(ws + off);    off += 11534336;  // 8192*704*2
  bf16* W1t = (bf16*)(ws + off);   off += 360448;    // 256*704*2
  bf16* W2f = (bf16*)(ws + off);   off += 1835008;   // 256*3584*2 (frag-major)
  bf16* W3t = (bf16*)(ws + off);   off += 114688;    // 16*3584*2
  float* H1 = (float*)(ws + off);  off += 8388608;   // 8192*256*4
  float* Hp = (float*)(ws + off);  off += 33554432;  // 4 x 8192*256*4
  float* part = (float*)(ws + off); off += 4194304;  // 8*16*8192*4

  prep_all<<<562, 256, 0, stream>>>(coef1, sb1, sp1, coef2, sb2, sp2,
                                    coef3, sb3, sp3, W1t, W2f, W3t);
  pool_basis1<<<2048, 256, 0, stream>>>(x, A1);
  gemm1s<<<dim3(4, 128), 256, 0, stream>>>(A1, W1t, b1, H1);
  kan_gemm2<<<dim3(128, 4), 512, 0, stream>>>(H1, W2f, Hp);
  kan_gemm3<<<dim3(128, 8), 256, 0, stream>>>(Hp, b2, W3t, part);
  lsm<<<32, 256, 0, stream>>>(part, b3, out);
}